// Round 6
// baseline (452.081 us; speedup 1.0000x reference)
//
#include <hip/hip_runtime.h>
#include <math.h>

// TriangleAttention (starting node): B=1, S=384, CZ=128, H=4, CH=32.
// I/O is fp32 (reference dtype); internal compute bf16 MFMA + fp32 softmax/LN.
// Pair bias (Wb) broadcasts along the softmax (key) axis -> softmax-invariant -> skipped.
// MFMA 16x16x32 bf16 layouts (verified m89/m91):
//   A: lane holds A[m=lane&15][k=(lane>>4)*8 + j], j=0..7
//   B: lane holds B[k=(lane>>4)*8 + j][n=lane&15]
//   C/D: col = lane&15, row = (lane>>4)*4 + reg
// R6: k2 QK^T operand-SWAPPED (S^T = mfma(K,Q), same fragment addresses) ->
// lane holds 4 CONSECUTIVE keys per acc reg for ONE j-row (l15). Softmax is
// in-lane + 2 shfls; P packs via v_cvt_pk_bf16_f32 into ds_write_b64 (zero
// extra bank conflicts at stride 72); PV as O^T = V^T P^T reads P contiguously.
// Kills the 96-f2bf + 96-conflicted-b16-write transform (R5's measured hog).

typedef unsigned short u16;
typedef __attribute__((ext_vector_type(8))) short short8;
typedef __attribute__((ext_vector_type(4))) short short4v;
typedef __attribute__((ext_vector_type(4))) float float4v;
typedef __attribute__((ext_vector_type(2))) unsigned uint2v;

union U8 { short8 s; u16 h[8]; };
union U4 { short4v s; u16 h[4]; };

__device__ __forceinline__ float bf2f(u16 x){
    unsigned v = ((unsigned)x) << 16;
    float f; __builtin_memcpy(&f, &v, 4);
    return f;
}
__device__ __forceinline__ u16 f2bf(float f){
    unsigned v; __builtin_memcpy(&v, &f, 4);
    unsigned r = (v + 0x7FFFu + ((v >> 16) & 1u)) >> 16;  // RNE
    return (u16)r;
}
__device__ __forceinline__ float exp2_fast(float x){
    float r; asm("v_exp_f32 %0, %1" : "=v"(r) : "v"(x));  // D = 2^S0
    return r;
}
__device__ __forceinline__ unsigned cvt_pk_bf16(float lo, float hi){
    unsigned r;
    asm("v_cvt_pk_bf16_f32 %0, %1, %2" : "=v"(r) : "v"(lo), "v"(hi));
    return r;
}
__device__ __forceinline__ short8 pack8f_s(const float* p, float s){
    const float4 a = ((const float4*)p)[0];
    const float4 b = ((const float4*)p)[1];
    U8 u;
    u.h[0]=f2bf(a.x*s); u.h[1]=f2bf(a.y*s); u.h[2]=f2bf(a.z*s); u.h[3]=f2bf(a.w*s);
    u.h[4]=f2bf(b.x*s); u.h[5]=f2bf(b.y*s); u.h[6]=f2bf(b.z*s); u.h[7]=f2bf(b.w*s);
    return u.s;
}

// ---------------------------------------------------------------------------
// k0a: convert {Wq*scale | Wk | Wv | Wg} fp32 -> bf16 into Wbf[320][128].
// Wq scale = 1/sqrt(32) * log2(e): softmax then runs in exp2 domain.
// ---------------------------------------------------------------------------
__global__ __launch_bounds__(256) void k0a_wconv(
    const float* __restrict__ Wq, const float* __restrict__ Wk,
    const float* __restrict__ Wv, const float* __restrict__ Wg,
    u16* __restrict__ Wbf)
{
    const int i = blockIdx.x * 256 + threadIdx.x;     // [0, 5120)
    const int e = i * 8;                              // element index (row-major 320x128)
    const int n = e >> 7, c0 = e & 127;
    const float* src; float s = 1.f;
    if (n < 128)      { src = Wq + n*128 + c0; s = 0.17677669529663689f * 1.4426950408889634f; }
    else if (n < 160) { src = Wk + (n-128)*128 + c0; }
    else if (n < 192) { src = Wv + (n-160)*128 + c0; }
    else              { src = Wg + (n-192)*128 + c0; }
    *(short8*)(Wbf + e) = pack8f_s(src, s);
}

// k0b: Wo fp32 -> bf16 (16384 elems). Runs after k2 (dest overlays dead KV space).
__global__ __launch_bounds__(256) void k0b_wconv(
    const float* __restrict__ Wo, u16* __restrict__ WoBf)
{
    const int e = (blockIdx.x * 256 + threadIdx.x) * 8;   // [0, 16384)
    *(short8*)(WoBf + e) = pack8f_s(Wo + e, 1.f);
}

// ---------------------------------------------------------------------------
// Kernel 1: LayerNorm + fused projection GEMM [64 rows x 320 cols], K=128.
// (unchanged from R3)
// ---------------------------------------------------------------------------
__global__ __launch_bounds__(256) void k1_ln_proj(
    const float* __restrict__ z, const float* __restrict__ lnw, const float* __restrict__ lnb,
    const u16* __restrict__ Wbf, const float* __restrict__ bg,
    u16* __restrict__ Qbuf, u16* __restrict__ KVbuf, u16* __restrict__ Gbuf)
{
    __shared__ __align__(16) u16 zn[64][136];   // +8 pad
    const int tid = threadIdx.x;
    const long rowg0 = (long)blockIdx.x * 64;

    {   // LayerNorm: 4 threads per row, 32 elems each, fp32 stats
        const int r = tid >> 2, p = tid & 3;
        const float* src = z + (rowg0 + r) * 128 + p * 32;
        float x[32];
        #pragma unroll
        for (int q = 0; q < 8; q++){
            const float4 v = ((const float4*)src)[q];
            x[q*4+0]=v.x; x[q*4+1]=v.y; x[q*4+2]=v.z; x[q*4+3]=v.w;
        }
        float s = 0.f, ss = 0.f;
        #pragma unroll
        for (int t = 0; t < 32; t++){ s += x[t]; ss += x[t]*x[t]; }
        s += __shfl_xor(s, 1);  ss += __shfl_xor(ss, 1);
        s += __shfl_xor(s, 2);  ss += __shfl_xor(ss, 2);
        const float mean = s * (1.f/128.f);
        const float var  = ss * (1.f/128.f) - mean*mean;
        const float rstd = rsqrtf(var + 1e-5f);
        #pragma unroll
        for (int t = 0; t < 32; t++){
            const int c = p*32 + t;
            zn[r][c] = f2bf((x[t]-mean)*rstd*lnw[c] + lnb[c]);
        }
    }
    __syncthreads();

    const int lane = tid & 63, wave = tid >> 6;
    const int l15 = lane & 15, quad = lane >> 4;

    short8 ZN[4][4];                      // 4 row-tiles x 4 k-steps
    #pragma unroll
    for (int m = 0; m < 4; m++)
        #pragma unroll
        for (int ks = 0; ks < 4; ks++)
            ZN[m][ks] = *(const short8*)&zn[m*16 + l15][ks*32 + quad*8];

    #pragma unroll
    for (int g = 0; g < 5; g++){
        const int nt = wave*5 + g;        // 0..19 : q(0-7) k(8-9) v(10-11) g(12-19)
        const u16* wp = Wbf + (nt*16 + l15)*128 + quad*8;
        short8 WF[4];
        #pragma unroll
        for (int ks = 0; ks < 4; ks++) WF[ks] = *(const short8*)(wp + ks*32);
        const int n0 = nt*16 + quad*4;    // 4 consecutive output channels per lane
        #pragma unroll
        for (int m = 0; m < 4; m++){
            float4v c = {0.f,0.f,0.f,0.f};
            #pragma unroll
            for (int ks = 0; ks < 4; ks++)
                c = __builtin_amdgcn_mfma_f32_16x16x32_bf16(WF[ks], ZN[m][ks], c, 0, 0, 0);
            const long row = rowg0 + m*16 + l15;
            if (nt < 8){                                   // Q (scale folded in Wbf)
                U4 u;
                #pragma unroll
                for (int r = 0; r < 4; r++) u.h[r] = f2bf(c[r]);
                *(short4v*)(Qbuf + row*128 + n0) = u.s;
            } else if (nt < 10){                           // K
                U4 u;
                #pragma unroll
                for (int r = 0; r < 4; r++) u.h[r] = f2bf(c[r]);
                *(short4v*)(KVbuf + row*64 + (n0 - 128)) = u.s;
            } else if (nt < 12){                           // V
                U4 u;
                #pragma unroll
                for (int r = 0; r < 4; r++) u.h[r] = f2bf(c[r]);
                *(short4v*)(KVbuf + row*64 + (n0 - 160) + 32) = u.s;
            } else {                                       // G = sigmoid(. + bg)
                const float4 b4 = *(const float4*)&bg[n0 - 192];
                U4 u;
                u.h[0] = f2bf(1.f/(1.f + __expf(-(c[0] + b4.x))));
                u.h[1] = f2bf(1.f/(1.f + __expf(-(c[1] + b4.y))));
                u.h[2] = f2bf(1.f/(1.f + __expf(-(c[2] + b4.z))));
                u.h[3] = f2bf(1.f/(1.f + __expf(-(c[3] + b4.w))));
                *(short4v*)(Gbuf + row*128 + (n0 - 192)) = u.s;
            }
        }
    }
}

// ---------------------------------------------------------------------------
// Kernel 2: attention. Block = (i, j-half), 512 threads = 8 waves; all 4
// heads share one K/V staging (head-independent). Wave w: head w>>1,
// j-tiles (jh*12 + (w&1)*6 + t)*16.
// Swapped QK^T: acc[kt] = S^T tile -> lane holds keys kt*16+quad*4+{0..3}
// of j-row l15. Softmax in-lane (exp2 domain) + shfl_xor(16,32).
// P -> Pj[wave][j=l15][64-key chunk] via cvt_pk + ds_write_b64 (conflict-free
// at stride 72). PV as O^T = V^T P^T (A=Vt b128, B=Pj b128). Per-wave
// in-order LDS on Pj -> no barrier. O = g*softmax*V in-place over Q.
// LDS: Ks 30720 + Vt 25088 + Pj 18432 = 74240 B.
// ---------------------------------------------------------------------------
__global__ __launch_bounds__(512, 4) void k2_attn(
    const u16* __restrict__ KVbuf, const u16* __restrict__ Gbuf, u16* __restrict__ QObuf)
{
    __shared__ __align__(16) u16 Ks[384][40];      // K [key][c], +8 pad        30720 B
    __shared__ __align__(16) u16 Vt[32][392];      // V^T [c][key], +8 pad      25088 B
    __shared__ __align__(16) u16 Pj[8][16][72];    // per-wave P [j][64key+8]   18432 B
    const int i = blockIdx.x >> 1, jh = blockIdx.x & 1;
    const int tid = threadIdx.x;
    const u16* kvsrc = KVbuf + (long)i * 384 * 64;
    {
        for (int idx = tid; idx < 384*8; idx += 512){
            const int k = idx >> 3, c8 = idx & 7;
            U8 d; d.s = *(const short8*)(kvsrc + k*64 + c8*8);
            if (c8 < 4) *(short8*)&Ks[k][c8*8] = d.s;
            else {
                const int c0 = (c8 - 4) * 8;
                #pragma unroll
                for (int jj = 0; jj < 8; jj++) Vt[c0 + jj][k] = d.h[jj];
            }
        }
    }
    __syncthreads();

    const int lane = tid & 63, wave = tid >> 6;
    const int l15 = lane & 15, quad = lane >> 4;
    const int h = wave >> 1, sub = wave & 1;
    const u16* qbase = QObuf + (long)i * 384 * 128 + h * 32;
    const u16* gbase = Gbuf  + (long)i * 384 * 128 + h * 32;
    u16* obase = QObuf + (long)i * 384 * 128 + h * 32;

    for (int t = 0; t < 6; t++){
        const int j0 = (jh*12 + sub*6 + t) * 16;
        // Q fragment (B-operand of swapped MFMA; same address as before)
        const short8 aq = *(const short8*)(qbase + (long)(j0 + l15)*128 + quad*8);
        float4v acc[24];
        #pragma unroll
        for (int kt = 0; kt < 24; kt++){
            const short8 bk = *(const short8*)&Ks[kt*16 + l15][quad*8];
            float4v zero = {0.f,0.f,0.f,0.f};
            acc[kt] = __builtin_amdgcn_mfma_f32_16x16x32_bf16(bk, aq, zero, 0, 0, 0);
        }
        // softmax over keys: lane holds 96 keys of row l15; quads hold the rest.
        float m0 = -1e30f, m1 = -1e30f, m2 = -1e30f, m3 = -1e30f;
        #pragma unroll
        for (int kt = 0; kt < 24; kt++){
            m0 = fmaxf(m0, acc[kt][0]); m1 = fmaxf(m1, acc[kt][1]);
            m2 = fmaxf(m2, acc[kt][2]); m3 = fmaxf(m3, acc[kt][3]);
        }
        float mx = fmaxf(fmaxf(m0, m1), fmaxf(m2, m3));
        mx = fmaxf(mx, __shfl_xor(mx, 16));
        mx = fmaxf(mx, __shfl_xor(mx, 32));
        float s0 = 0.f, s1 = 0.f, s2 = 0.f, s3 = 0.f;
        #pragma unroll
        for (int kt = 0; kt < 24; kt++){
            acc[kt][0] = exp2_fast(acc[kt][0] - mx); s0 += acc[kt][0];
            acc[kt][1] = exp2_fast(acc[kt][1] - mx); s1 += acc[kt][1];
            acc[kt][2] = exp2_fast(acc[kt][2] - mx); s2 += acc[kt][2];
            acc[kt][3] = exp2_fast(acc[kt][3] - mx); s3 += acc[kt][3];
        }
        float sum = (s0 + s1) + (s2 + s3);
        sum += __shfl_xor(sum, 16);
        sum += __shfl_xor(sum, 32);
        const float inv = 1.f / sum;   // one scalar per lane (row l15)

        // PV in 6 groups of 64 keys: pack (cvt_pk) -> Pj b64 write -> b128 read
        float4v oacc[2] = {{0.f,0.f,0.f,0.f},{0.f,0.f,0.f,0.f}};
        #pragma unroll
        for (int g6 = 0; g6 < 6; g6++){
            #pragma unroll
            for (int kk = 0; kk < 4; kk++){
                const int kt = g6*4 + kk;
                uint2v d;
                d.x = cvt_pk_bf16(acc[kt][0], acc[kt][1]);
                d.y = cvt_pk_bf16(acc[kt][2], acc[kt][3]);
                *(uint2v*)&Pj[wave][l15][kk*16 + quad*4] = d;   // keys kk*16+quad*4..+3
            }
            #pragma unroll
            for (int kc = 0; kc < 2; kc++){
                const short8 bp = *(const short8*)&Pj[wave][l15][kc*32 + quad*8];
                const int ch = g6*2 + kc;                       // global 32-key chunk
                #pragma unroll
                for (int ct = 0; ct < 2; ct++){
                    const short8 av = *(const short8*)&Vt[ct*16 + l15][ch*32 + quad*8];
                    oacc[ct] = __builtin_amdgcn_mfma_f32_16x16x32_bf16(av, bp, oacc[ct], 0, 0, 0);
                }
            }
        }
        // epilogue: lane holds O^T[c=ct*16+quad*4+r][j=l15] -> 8B gate load,
        // normalize by inv (uniform per lane), 8B store in-place over Q.
        #pragma unroll
        for (int ct = 0; ct < 2; ct++){
            const int c0 = ct*16 + quad*4;
            const long roff = (long)(j0 + l15)*128 + c0;
            U4 g4; g4.s = *(const short4v*)(gbase + roff);
            const float o0 = bf2f(g4.h[0]) * (oacc[ct][0] * inv);
            const float o1 = bf2f(g4.h[1]) * (oacc[ct][1] * inv);
            const float o2 = bf2f(g4.h[2]) * (oacc[ct][2] * inv);
            const float o3 = bf2f(g4.h[3]) * (oacc[ct][3] * inv);
            uint2v st;
            st.x = cvt_pk_bf16(o0, o1);
            st.y = cvt_pk_bf16(o2, o3);
            *(uint2v*)(obase + roff) = st;
        }
    }
}

// ---------------------------------------------------------------------------
// Kernel 3: out = O' @ Wo^T + bo   [147456x128]@[128x128] -> fp32 d_out
// (unchanged from R3)
// ---------------------------------------------------------------------------
__global__ __launch_bounds__(256) void k3_outproj(
    const u16* __restrict__ Obuf, const u16* __restrict__ WoBf, const float* __restrict__ bo,
    float* __restrict__ out)
{
    const int tid = threadIdx.x, lane = tid & 63, wave = tid >> 6;
    const int l15 = lane & 15, quad = lane >> 4;
    const long row0 = (long)blockIdx.x * 64;
    short8 WF[2][4];
    #pragma unroll
    for (int g = 0; g < 2; g++){
        const u16* wp = WoBf + ((wave*2 + g)*16 + l15)*128 + quad*8;
        #pragma unroll
        for (int ks = 0; ks < 4; ks++) WF[g][ks] = *(const short8*)(wp + ks*32);
    }
    #pragma unroll
    for (int m = 0; m < 4; m++){
        short8 OF[4];
        const u16* ap = Obuf + (row0 + m*16 + l15)*128 + quad*8;
        #pragma unroll
        for (int ks = 0; ks < 4; ks++) OF[ks] = *(const short8*)(ap + ks*32);
        #pragma unroll
        for (int g = 0; g < 2; g++){
            float4v c = {0.f,0.f,0.f,0.f};
            #pragma unroll
            for (int ks = 0; ks < 4; ks++)
                c = __builtin_amdgcn_mfma_f32_16x16x32_bf16(WF[g][ks], OF[ks], c, 0, 0, 0);
            const int n0 = (wave*2 + g)*16 + quad*4;
            const float4 b4 = *(const float4*)&bo[n0];
            const long row = row0 + m*16 + l15;
            float4 o4;
            o4.x = c[0] + b4.x; o4.y = c[1] + b4.y;
            o4.z = c[2] + b4.z; o4.w = c[3] + b4.w;
            *(float4*)(out + row*128 + n0) = o4;
        }
    }
}

extern "C" void kernel_launch(void* const* d_in, const int* in_sizes, int n_in,
                              void* d_out, int out_size, void* d_ws, size_t ws_size,
                              hipStream_t stream)
{
    (void)in_sizes; (void)n_in; (void)out_size; (void)ws_size;
    const float* z   = (const float*)d_in[0];
    const float* lnw = (const float*)d_in[1];
    const float* lnb = (const float*)d_in[2];
    const float* Wq  = (const float*)d_in[3];
    const float* Wk  = (const float*)d_in[4];
    const float* Wv  = (const float*)d_in[5];
    // d_in[6] = Wb : softmax-invariant (broadcast along key axis) -> unused
    const float* Wg  = (const float*)d_in[7];
    const float* bg  = (const float*)d_in[8];
    const float* Wo  = (const float*)d_in[9];
    const float* bo  = (const float*)d_in[10];

    u16* Qbuf = (u16*)d_ws;                   // 147456*128 bf16 (Q, later O' in-place)
    u16* KV   = Qbuf + 147456L*128;           // 147456*64  bf16 (k | v)
    // G lives in d_out's front half (bf16, consumed by k2 before k3 overwrites
    // d_out with fp32 results). Wbf (320x128 bf16 = 80KB) lives right after G.
    u16* Gbuf = (u16*)d_out;                  // 147456*128 bf16 = 37.7MB < 75.5MB
    u16* Wbf  = Gbuf + 147456L*128;           // 40960 u16 = 80KB
    // WoBf overlays the (dead-after-k2) front of the KV region.
    u16* WoBf = KV;                           // 16384 u16 = 32KB

    k0a_wconv<<<dim3(20), dim3(256), 0, stream>>>(Wq, Wk, Wv, Wg, Wbf);
    k1_ln_proj<<<dim3(2304), dim3(256), 0, stream>>>(z, lnw, lnb, Wbf, bg,
                                                     Qbuf, KV, Gbuf);
    k2_attn<<<dim3(768), dim3(512), 0, stream>>>(KV, Gbuf, Qbuf);
    k0b_wconv<<<dim3(8), dim3(256), 0, stream>>>(Wo, WoBf);
    k3_outproj<<<dim3(2304), dim3(256), 0, stream>>>(Qbuf, WoBf, bo, (float*)d_out);
}

// Round 7
// 448.006 us; speedup vs baseline: 1.0091x; 1.0091x over previous
//
#include <hip/hip_runtime.h>
#include <math.h>

// TriangleAttention (starting node): B=1, S=384, CZ=128, H=4, CH=32.
// I/O is fp32 (reference dtype); internal compute bf16 MFMA + fp32 softmax/LN.
// Pair bias (Wb) broadcasts along the softmax (key) axis -> softmax-invariant -> skipped.
// MFMA 16x16x32 bf16 layouts (verified m89/m91):
//   A: lane holds A[m=lane&15][k=(lane>>4)*8 + j], j=0..7
//   B: lane holds B[k=(lane>>4)*8 + j][n=lane&15]
//   C/D: col = lane&15, row = (lane>>4)*4 + reg
// R7 = R6 structure minus the inline-asm cvt_pk (which forced AGPR->VGPR
// copies of the whole accumulator, blew the (512,4) arch-VGPR cap and
// spilled to scratch: FETCH 56->528MB, dur 115->225us). Packing now plain C
// (f2bf pair -> u32): compiler reads AGPRs directly, no forced copies.
// k2: swapped QK^T (S^T = mfma(K,Q)) -> lane holds 4 consecutive keys of one
// j-row; in-lane softmax + 2 shfls; P -> Pj b64 writes; PV as O^T = V^T P^T.

typedef unsigned short u16;
typedef __attribute__((ext_vector_type(8))) short short8;
typedef __attribute__((ext_vector_type(4))) short short4v;
typedef __attribute__((ext_vector_type(4))) float float4v;
typedef __attribute__((ext_vector_type(2))) unsigned uint2v;

union U8 { short8 s; u16 h[8]; };
union U4 { short4v s; u16 h[4]; };

__device__ __forceinline__ float bf2f(u16 x){
    unsigned v = ((unsigned)x) << 16;
    float f; __builtin_memcpy(&f, &v, 4);
    return f;
}
__device__ __forceinline__ u16 f2bf(float f){
    unsigned v; __builtin_memcpy(&v, &f, 4);
    unsigned r = (v + 0x7FFFu + ((v >> 16) & 1u)) >> 16;  // RNE
    return (u16)r;
}
__device__ __forceinline__ unsigned pk2(float lo, float hi){   // plain C, no asm
    return (unsigned)f2bf(lo) | ((unsigned)f2bf(hi) << 16);
}
__device__ __forceinline__ float exp2_fast(float x){
    float r; asm("v_exp_f32 %0, %1" : "=v"(r) : "v"(x));  // D = 2^S0
    return r;
}
__device__ __forceinline__ short8 pack8f_s(const float* p, float s){
    const float4 a = ((const float4*)p)[0];
    const float4 b = ((const float4*)p)[1];
    U8 u;
    u.h[0]=f2bf(a.x*s); u.h[1]=f2bf(a.y*s); u.h[2]=f2bf(a.z*s); u.h[3]=f2bf(a.w*s);
    u.h[4]=f2bf(b.x*s); u.h[5]=f2bf(b.y*s); u.h[6]=f2bf(b.z*s); u.h[7]=f2bf(b.w*s);
    return u.s;
}

// ---------------------------------------------------------------------------
// k0a: convert {Wq*scale | Wk | Wv | Wg} fp32 -> bf16 into Wbf[320][128].
// Wq scale = 1/sqrt(32) * log2(e): softmax then runs in exp2 domain.
// ---------------------------------------------------------------------------
__global__ __launch_bounds__(256) void k0a_wconv(
    const float* __restrict__ Wq, const float* __restrict__ Wk,
    const float* __restrict__ Wv, const float* __restrict__ Wg,
    u16* __restrict__ Wbf)
{
    const int i = blockIdx.x * 256 + threadIdx.x;     // [0, 5120)
    const int e = i * 8;                              // element index (row-major 320x128)
    const int n = e >> 7, c0 = e & 127;
    const float* src; float s = 1.f;
    if (n < 128)      { src = Wq + n*128 + c0; s = 0.17677669529663689f * 1.4426950408889634f; }
    else if (n < 160) { src = Wk + (n-128)*128 + c0; }
    else if (n < 192) { src = Wv + (n-160)*128 + c0; }
    else              { src = Wg + (n-192)*128 + c0; }
    *(short8*)(Wbf + e) = pack8f_s(src, s);
}

// k0b: Wo fp32 -> bf16 (16384 elems). Runs after k2 (dest overlays dead KV space).
__global__ __launch_bounds__(256) void k0b_wconv(
    const float* __restrict__ Wo, u16* __restrict__ WoBf)
{
    const int e = (blockIdx.x * 256 + threadIdx.x) * 8;   // [0, 16384)
    *(short8*)(WoBf + e) = pack8f_s(Wo + e, 1.f);
}

// ---------------------------------------------------------------------------
// Kernel 1: LayerNorm + fused projection GEMM [64 rows x 320 cols], K=128.
// (unchanged from R3)
// ---------------------------------------------------------------------------
__global__ __launch_bounds__(256) void k1_ln_proj(
    const float* __restrict__ z, const float* __restrict__ lnw, const float* __restrict__ lnb,
    const u16* __restrict__ Wbf, const float* __restrict__ bg,
    u16* __restrict__ Qbuf, u16* __restrict__ KVbuf, u16* __restrict__ Gbuf)
{
    __shared__ __align__(16) u16 zn[64][136];   // +8 pad
    const int tid = threadIdx.x;
    const long rowg0 = (long)blockIdx.x * 64;

    {   // LayerNorm: 4 threads per row, 32 elems each, fp32 stats
        const int r = tid >> 2, p = tid & 3;
        const float* src = z + (rowg0 + r) * 128 + p * 32;
        float x[32];
        #pragma unroll
        for (int q = 0; q < 8; q++){
            const float4 v = ((const float4*)src)[q];
            x[q*4+0]=v.x; x[q*4+1]=v.y; x[q*4+2]=v.z; x[q*4+3]=v.w;
        }
        float s = 0.f, ss = 0.f;
        #pragma unroll
        for (int t = 0; t < 32; t++){ s += x[t]; ss += x[t]*x[t]; }
        s += __shfl_xor(s, 1);  ss += __shfl_xor(ss, 1);
        s += __shfl_xor(s, 2);  ss += __shfl_xor(ss, 2);
        const float mean = s * (1.f/128.f);
        const float var  = ss * (1.f/128.f) - mean*mean;
        const float rstd = rsqrtf(var + 1e-5f);
        #pragma unroll
        for (int t = 0; t < 32; t++){
            const int c = p*32 + t;
            zn[r][c] = f2bf((x[t]-mean)*rstd*lnw[c] + lnb[c]);
        }
    }
    __syncthreads();

    const int lane = tid & 63, wave = tid >> 6;
    const int l15 = lane & 15, quad = lane >> 4;

    short8 ZN[4][4];                      // 4 row-tiles x 4 k-steps
    #pragma unroll
    for (int m = 0; m < 4; m++)
        #pragma unroll
        for (int ks = 0; ks < 4; ks++)
            ZN[m][ks] = *(const short8*)&zn[m*16 + l15][ks*32 + quad*8];

    #pragma unroll
    for (int g = 0; g < 5; g++){
        const int nt = wave*5 + g;        // 0..19 : q(0-7) k(8-9) v(10-11) g(12-19)
        const u16* wp = Wbf + (nt*16 + l15)*128 + quad*8;
        short8 WF[4];
        #pragma unroll
        for (int ks = 0; ks < 4; ks++) WF[ks] = *(const short8*)(wp + ks*32);
        const int n0 = nt*16 + quad*4;    // 4 consecutive output channels per lane
        #pragma unroll
        for (int m = 0; m < 4; m++){
            float4v c = {0.f,0.f,0.f,0.f};
            #pragma unroll
            for (int ks = 0; ks < 4; ks++)
                c = __builtin_amdgcn_mfma_f32_16x16x32_bf16(WF[ks], ZN[m][ks], c, 0, 0, 0);
            const long row = rowg0 + m*16 + l15;
            if (nt < 8){                                   // Q (scale folded in Wbf)
                U4 u;
                #pragma unroll
                for (int r = 0; r < 4; r++) u.h[r] = f2bf(c[r]);
                *(short4v*)(Qbuf + row*128 + n0) = u.s;
            } else if (nt < 10){                           // K
                U4 u;
                #pragma unroll
                for (int r = 0; r < 4; r++) u.h[r] = f2bf(c[r]);
                *(short4v*)(KVbuf + row*64 + (n0 - 128)) = u.s;
            } else if (nt < 12){                           // V
                U4 u;
                #pragma unroll
                for (int r = 0; r < 4; r++) u.h[r] = f2bf(c[r]);
                *(short4v*)(KVbuf + row*64 + (n0 - 160) + 32) = u.s;
            } else {                                       // G = sigmoid(. + bg)
                const float4 b4 = *(const float4*)&bg[n0 - 192];
                U4 u;
                u.h[0] = f2bf(1.f/(1.f + __expf(-(c[0] + b4.x))));
                u.h[1] = f2bf(1.f/(1.f + __expf(-(c[1] + b4.y))));
                u.h[2] = f2bf(1.f/(1.f + __expf(-(c[2] + b4.z))));
                u.h[3] = f2bf(1.f/(1.f + __expf(-(c[3] + b4.w))));
                *(short4v*)(Gbuf + row*128 + (n0 - 192)) = u.s;
            }
        }
    }
}

// ---------------------------------------------------------------------------
// Kernel 2: attention. Block = (i, j-half), 512 threads = 8 waves; all 4
// heads share one K/V staging (head-independent). Wave w: head w>>1,
// j-tiles (jh*12 + (w&1)*6 + t)*16.
// Swapped QK^T: acc[kt] = S^T tile -> lane holds keys kt*16+quad*4+{0..3}
// of j-row l15. Softmax in-lane (exp2 domain) + shfl_xor(16,32).
// P -> Pj[wave][j=l15][64-key chunk] via plain-C pk2 + ds_write_b64.
// PV as O^T = V^T P^T (A=Vt b128, B=Pj b128). Per-wave in-order LDS on Pj.
// O = g*softmax*V in-place over Q. LDS: Ks 30720 + Vt 25088 + Pj 18432 = 74240 B.
// ---------------------------------------------------------------------------
__global__ __launch_bounds__(512, 4) void k2_attn(
    const u16* __restrict__ KVbuf, const u16* __restrict__ Gbuf, u16* __restrict__ QObuf)
{
    __shared__ __align__(16) u16 Ks[384][40];      // K [key][c], +8 pad        30720 B
    __shared__ __align__(16) u16 Vt[32][392];      // V^T [c][key], +8 pad      25088 B
    __shared__ __align__(16) u16 Pj[8][16][72];    // per-wave P [j][64key+8]   18432 B
    const int i = blockIdx.x >> 1, jh = blockIdx.x & 1;
    const int tid = threadIdx.x;
    const u16* kvsrc = KVbuf + (long)i * 384 * 64;
    {
        for (int idx = tid; idx < 384*8; idx += 512){
            const int k = idx >> 3, c8 = idx & 7;
            U8 d; d.s = *(const short8*)(kvsrc + k*64 + c8*8);
            if (c8 < 4) *(short8*)&Ks[k][c8*8] = d.s;
            else {
                const int c0 = (c8 - 4) * 8;
                #pragma unroll
                for (int jj = 0; jj < 8; jj++) Vt[c0 + jj][k] = d.h[jj];
            }
        }
    }
    __syncthreads();

    const int lane = tid & 63, wave = tid >> 6;
    const int l15 = lane & 15, quad = lane >> 4;
    const int h = wave >> 1, sub = wave & 1;
    const u16* qbase = QObuf + (long)i * 384 * 128 + h * 32;
    const u16* gbase = Gbuf  + (long)i * 384 * 128 + h * 32;
    u16* obase = QObuf + (long)i * 384 * 128 + h * 32;

    for (int t = 0; t < 6; t++){
        const int j0 = (jh*12 + sub*6 + t) * 16;
        // Q fragment (B-operand of swapped MFMA)
        const short8 aq = *(const short8*)(qbase + (long)(j0 + l15)*128 + quad*8);
        float4v acc[24];
        #pragma unroll
        for (int kt = 0; kt < 24; kt++){
            const short8 bk = *(const short8*)&Ks[kt*16 + l15][quad*8];
            float4v zero = {0.f,0.f,0.f,0.f};
            acc[kt] = __builtin_amdgcn_mfma_f32_16x16x32_bf16(bk, aq, zero, 0, 0, 0);
        }
        // softmax over keys: lane holds 96 keys of row l15; quads hold the rest.
        float m0 = -1e30f, m1 = -1e30f, m2 = -1e30f, m3 = -1e30f;
        #pragma unroll
        for (int kt = 0; kt < 24; kt++){
            m0 = fmaxf(m0, acc[kt][0]); m1 = fmaxf(m1, acc[kt][1]);
            m2 = fmaxf(m2, acc[kt][2]); m3 = fmaxf(m3, acc[kt][3]);
        }
        float mx = fmaxf(fmaxf(m0, m1), fmaxf(m2, m3));
        mx = fmaxf(mx, __shfl_xor(mx, 16));
        mx = fmaxf(mx, __shfl_xor(mx, 32));
        float s0 = 0.f, s1 = 0.f, s2 = 0.f, s3 = 0.f;
        #pragma unroll
        for (int kt = 0; kt < 24; kt++){
            acc[kt][0] = exp2_fast(acc[kt][0] - mx); s0 += acc[kt][0];
            acc[kt][1] = exp2_fast(acc[kt][1] - mx); s1 += acc[kt][1];
            acc[kt][2] = exp2_fast(acc[kt][2] - mx); s2 += acc[kt][2];
            acc[kt][3] = exp2_fast(acc[kt][3] - mx); s3 += acc[kt][3];
        }
        float sum = (s0 + s1) + (s2 + s3);
        sum += __shfl_xor(sum, 16);
        sum += __shfl_xor(sum, 32);
        const float inv = 1.f / sum;   // one scalar per lane (row l15)

        // PV in 6 groups of 64 keys: pack (plain C) -> Pj b64 write -> b128 read
        float4v oacc[2] = {{0.f,0.f,0.f,0.f},{0.f,0.f,0.f,0.f}};
        #pragma unroll
        for (int g6 = 0; g6 < 6; g6++){
            #pragma unroll
            for (int kk = 0; kk < 4; kk++){
                const int kt = g6*4 + kk;
                uint2v d;
                d.x = pk2(acc[kt][0], acc[kt][1]);
                d.y = pk2(acc[kt][2], acc[kt][3]);
                *(uint2v*)&Pj[wave][l15][kk*16 + quad*4] = d;   // keys kk*16+quad*4..+3
            }
            #pragma unroll
            for (int kc = 0; kc < 2; kc++){
                const short8 bp = *(const short8*)&Pj[wave][l15][kc*32 + quad*8];
                const int ch = g6*2 + kc;                       // global 32-key chunk
                #pragma unroll
                for (int ct = 0; ct < 2; ct++){
                    const short8 av = *(const short8*)&Vt[ct*16 + l15][ch*32 + quad*8];
                    oacc[ct] = __builtin_amdgcn_mfma_f32_16x16x32_bf16(av, bp, oacc[ct], 0, 0, 0);
                }
            }
        }
        // epilogue: lane holds O^T[c=ct*16+quad*4+r][j=l15] -> 8B gate load,
        // normalize by inv (uniform per lane), 8B store in-place over Q.
        #pragma unroll
        for (int ct = 0; ct < 2; ct++){
            const int c0 = ct*16 + quad*4;
            const long roff = (long)(j0 + l15)*128 + c0;
            U4 g4; g4.s = *(const short4v*)(gbase + roff);
            const float o0 = bf2f(g4.h[0]) * (oacc[ct][0] * inv);
            const float o1 = bf2f(g4.h[1]) * (oacc[ct][1] * inv);
            const float o2 = bf2f(g4.h[2]) * (oacc[ct][2] * inv);
            const float o3 = bf2f(g4.h[3]) * (oacc[ct][3] * inv);
            uint2v st;
            st.x = pk2(o0, o1);
            st.y = pk2(o2, o3);
            *(uint2v*)(obase + roff) = st;
        }
    }
}

// ---------------------------------------------------------------------------
// Kernel 3: out = O' @ Wo^T + bo   [147456x128]@[128x128] -> fp32 d_out
// (unchanged from R3)
// ---------------------------------------------------------------------------
__global__ __launch_bounds__(256) void k3_outproj(
    const u16* __restrict__ Obuf, const u16* __restrict__ WoBf, const float* __restrict__ bo,
    float* __restrict__ out)
{
    const int tid = threadIdx.x, lane = tid & 63, wave = tid >> 6;
    const int l15 = lane & 15, quad = lane >> 4;
    const long row0 = (long)blockIdx.x * 64;
    short8 WF[2][4];
    #pragma unroll
    for (int g = 0; g < 2; g++){
        const u16* wp = WoBf + ((wave*2 + g)*16 + l15)*128 + quad*8;
        #pragma unroll
        for (int ks = 0; ks < 4; ks++) WF[g][ks] = *(const short8*)(wp + ks*32);
    }
    #pragma unroll
    for (int m = 0; m < 4; m++){
        short8 OF[4];
        const u16* ap = Obuf + (row0 + m*16 + l15)*128 + quad*8;
        #pragma unroll
        for (int ks = 0; ks < 4; ks++) OF[ks] = *(const short8*)(ap + ks*32);
        #pragma unroll
        for (int g = 0; g < 2; g++){
            float4v c = {0.f,0.f,0.f,0.f};
            #pragma unroll
            for (int ks = 0; ks < 4; ks++)
                c = __builtin_amdgcn_mfma_f32_16x16x32_bf16(WF[g][ks], OF[ks], c, 0, 0, 0);
            const int n0 = (wave*2 + g)*16 + quad*4;
            const float4 b4 = *(const float4*)&bo[n0];
            const long row = row0 + m*16 + l15;
            float4 o4;
            o4.x = c[0] + b4.x; o4.y = c[1] + b4.y;
            o4.z = c[2] + b4.z; o4.w = c[3] + b4.w;
            *(float4*)(out + row*128 + n0) = o4;
        }
    }
}

extern "C" void kernel_launch(void* const* d_in, const int* in_sizes, int n_in,
                              void* d_out, int out_size, void* d_ws, size_t ws_size,
                              hipStream_t stream)
{
    (void)in_sizes; (void)n_in; (void)out_size; (void)ws_size;
    const float* z   = (const float*)d_in[0];
    const float* lnw = (const float*)d_in[1];
    const float* lnb = (const float*)d_in[2];
    const float* Wq  = (const float*)d_in[3];
    const float* Wk  = (const float*)d_in[4];
    const float* Wv  = (const float*)d_in[5];
    // d_in[6] = Wb : softmax-invariant (broadcast along key axis) -> unused
    const float* Wg  = (const float*)d_in[7];
    const float* bg  = (const float*)d_in[8];
    const float* Wo  = (const float*)d_in[9];
    const float* bo  = (const float*)d_in[10];

    u16* Qbuf = (u16*)d_ws;                   // 147456*128 bf16 (Q, later O' in-place)
    u16* KV   = Qbuf + 147456L*128;           // 147456*64  bf16 (k | v)
    // G lives in d_out's front half (bf16, consumed by k2 before k3 overwrites
    // d_out with fp32 results). Wbf (320x128 bf16 = 80KB) lives right after G.
    u16* Gbuf = (u16*)d_out;                  // 147456*128 bf16 = 37.7MB < 75.5MB
    u16* Wbf  = Gbuf + 147456L*128;           // 40960 u16 = 80KB
    // WoBf overlays the (dead-after-k2) front of the KV region.
    u16* WoBf = KV;                           // 16384 u16 = 32KB

    k0a_wconv<<<dim3(20), dim3(256), 0, stream>>>(Wq, Wk, Wv, Wg, Wbf);
    k1_ln_proj<<<dim3(2304), dim3(256), 0, stream>>>(z, lnw, lnb, Wbf, bg,
                                                     Qbuf, KV, Gbuf);
    k2_attn<<<dim3(768), dim3(512), 0, stream>>>(KV, Gbuf, Qbuf);
    k0b_wconv<<<dim3(8), dim3(256), 0, stream>>>(Wo, WoBf);
    k3_outproj<<<dim3(2304), dim3(256), 0, stream>>>(Qbuf, WoBf, bo, (float*)d_out);
}

// Round 8
// 326.111 us; speedup vs baseline: 1.3863x; 1.3738x over previous
//
#include <hip/hip_runtime.h>
#include <math.h>

// TriangleAttention (starting node): B=1, S=384, CZ=128, H=4, CH=32.
// I/O is fp32 (reference dtype); internal compute bf16 MFMA + fp32 softmax/LN.
// Pair bias (Wb) broadcasts along the softmax (key) axis -> softmax-invariant -> skipped.
// MFMA 16x16x32 bf16 layouts (verified m89/m91):
//   A: lane holds A[m=lane&15][k=(lane>>4)*8 + j], j=0..7
//   B: lane holds B[k=(lane>>4)*8 + j][n=lane&15]
//   C/D: col = lane&15, row = (lane>>4)*4 + reg
// R8: k2 REVERTED to the R5 version (115us verified; R6/R7's swapped-QKT
// rewrite caused ~460MB of scratch-like HBM traffic regardless of asm/C
// packing -> abandoned). k1 gets __launch_bounds__(256,2) (deeper W-group
// pipelining; measured residency 4.7 waves/CU < the 8-wave floor so the cap
// can't bind). k3 grid-strided x2 with W/bias hoisted (halves W-load latency
// exposure, longer-lived blocks).

typedef unsigned short u16;
typedef __attribute__((ext_vector_type(8))) short short8;
typedef __attribute__((ext_vector_type(4))) short short4v;
typedef __attribute__((ext_vector_type(4))) float float4v;

union U8 { short8 s; u16 h[8]; };
union U4 { short4v s; u16 h[4]; };

__device__ __forceinline__ float bf2f(u16 x){
    unsigned v = ((unsigned)x) << 16;
    float f; __builtin_memcpy(&f, &v, 4);
    return f;
}
__device__ __forceinline__ u16 f2bf(float f){
    unsigned v; __builtin_memcpy(&v, &f, 4);
    unsigned r = (v + 0x7FFFu + ((v >> 16) & 1u)) >> 16;  // RNE
    return (u16)r;
}
__device__ __forceinline__ float exp2_fast(float x){
    float r; asm("v_exp_f32 %0, %1" : "=v"(r) : "v"(x));  // D = 2^S0
    return r;
}
__device__ __forceinline__ short8 pack8f_s(const float* p, float s){
    const float4 a = ((const float4*)p)[0];
    const float4 b = ((const float4*)p)[1];
    U8 u;
    u.h[0]=f2bf(a.x*s); u.h[1]=f2bf(a.y*s); u.h[2]=f2bf(a.z*s); u.h[3]=f2bf(a.w*s);
    u.h[4]=f2bf(b.x*s); u.h[5]=f2bf(b.y*s); u.h[6]=f2bf(b.z*s); u.h[7]=f2bf(b.w*s);
    return u.s;
}

// ---------------------------------------------------------------------------
// k0a: convert {Wq*scale | Wk | Wv | Wg} fp32 -> bf16 into Wbf[320][128].
// Wq scale = 1/sqrt(32) * log2(e): softmax then runs in exp2 domain.
// ---------------------------------------------------------------------------
__global__ __launch_bounds__(256) void k0a_wconv(
    const float* __restrict__ Wq, const float* __restrict__ Wk,
    const float* __restrict__ Wv, const float* __restrict__ Wg,
    u16* __restrict__ Wbf)
{
    const int i = blockIdx.x * 256 + threadIdx.x;     // [0, 5120)
    const int e = i * 8;                              // element index (row-major 320x128)
    const int n = e >> 7, c0 = e & 127;
    const float* src; float s = 1.f;
    if (n < 128)      { src = Wq + n*128 + c0; s = 0.17677669529663689f * 1.4426950408889634f; }
    else if (n < 160) { src = Wk + (n-128)*128 + c0; }
    else if (n < 192) { src = Wv + (n-160)*128 + c0; }
    else              { src = Wg + (n-192)*128 + c0; }
    *(short8*)(Wbf + e) = pack8f_s(src, s);
}

// k0b: Wo fp32 -> bf16 (16384 elems). Runs after k2 (dest overlays dead KV space).
__global__ __launch_bounds__(256) void k0b_wconv(
    const float* __restrict__ Wo, u16* __restrict__ WoBf)
{
    const int e = (blockIdx.x * 256 + threadIdx.x) * 8;   // [0, 16384)
    *(short8*)(WoBf + e) = pack8f_s(Wo + e, 1.f);
}

// ---------------------------------------------------------------------------
// Kernel 1: LayerNorm + fused projection GEMM [64 rows x 320 cols], K=128.
// R8: __launch_bounds__(256,2) -> VGPR budget up to 256 so the compiler can
// software-pipeline the 5 W-groups (was VGPR 104 ~ 1 group in flight).
// 8-wave/CU floor > measured 4.7 waves/CU residency, so the cap cannot bind.
// ---------------------------------------------------------------------------
__global__ __launch_bounds__(256, 2) void k1_ln_proj(
    const float* __restrict__ z, const float* __restrict__ lnw, const float* __restrict__ lnb,
    const u16* __restrict__ Wbf, const float* __restrict__ bg,
    u16* __restrict__ Qbuf, u16* __restrict__ KVbuf, u16* __restrict__ Gbuf)
{
    __shared__ __align__(16) u16 zn[64][136];   // +8 pad
    const int tid = threadIdx.x;
    const long rowg0 = (long)blockIdx.x * 64;

    {   // LayerNorm: 4 threads per row, 32 elems each, fp32 stats
        const int r = tid >> 2, p = tid & 3;
        const float* src = z + (rowg0 + r) * 128 + p * 32;
        float x[32];
        #pragma unroll
        for (int q = 0; q < 8; q++){
            const float4 v = ((const float4*)src)[q];
            x[q*4+0]=v.x; x[q*4+1]=v.y; x[q*4+2]=v.z; x[q*4+3]=v.w;
        }
        float s = 0.f, ss = 0.f;
        #pragma unroll
        for (int t = 0; t < 32; t++){ s += x[t]; ss += x[t]*x[t]; }
        s += __shfl_xor(s, 1);  ss += __shfl_xor(ss, 1);
        s += __shfl_xor(s, 2);  ss += __shfl_xor(ss, 2);
        const float mean = s * (1.f/128.f);
        const float var  = ss * (1.f/128.f) - mean*mean;
        const float rstd = rsqrtf(var + 1e-5f);
        #pragma unroll
        for (int t = 0; t < 32; t++){
            const int c = p*32 + t;
            zn[r][c] = f2bf((x[t]-mean)*rstd*lnw[c] + lnb[c]);
        }
    }
    __syncthreads();

    const int lane = tid & 63, wave = tid >> 6;
    const int l15 = lane & 15, quad = lane >> 4;

    short8 ZN[4][4];                      // 4 row-tiles x 4 k-steps
    #pragma unroll
    for (int m = 0; m < 4; m++)
        #pragma unroll
        for (int ks = 0; ks < 4; ks++)
            ZN[m][ks] = *(const short8*)&zn[m*16 + l15][ks*32 + quad*8];

    #pragma unroll
    for (int g = 0; g < 5; g++){
        const int nt = wave*5 + g;        // 0..19 : q(0-7) k(8-9) v(10-11) g(12-19)
        const u16* wp = Wbf + (nt*16 + l15)*128 + quad*8;
        short8 WF[4];
        #pragma unroll
        for (int ks = 0; ks < 4; ks++) WF[ks] = *(const short8*)(wp + ks*32);
        const int n0 = nt*16 + quad*4;    // 4 consecutive output channels per lane
        #pragma unroll
        for (int m = 0; m < 4; m++){
            float4v c = {0.f,0.f,0.f,0.f};
            #pragma unroll
            for (int ks = 0; ks < 4; ks++)
                c = __builtin_amdgcn_mfma_f32_16x16x32_bf16(WF[ks], ZN[m][ks], c, 0, 0, 0);
            const long row = rowg0 + m*16 + l15;
            if (nt < 8){                                   // Q (scale folded in Wbf)
                U4 u;
                #pragma unroll
                for (int r = 0; r < 4; r++) u.h[r] = f2bf(c[r]);
                *(short4v*)(Qbuf + row*128 + n0) = u.s;
            } else if (nt < 10){                           // K
                U4 u;
                #pragma unroll
                for (int r = 0; r < 4; r++) u.h[r] = f2bf(c[r]);
                *(short4v*)(KVbuf + row*64 + (n0 - 128)) = u.s;
            } else if (nt < 12){                           // V
                U4 u;
                #pragma unroll
                for (int r = 0; r < 4; r++) u.h[r] = f2bf(c[r]);
                *(short4v*)(KVbuf + row*64 + (n0 - 160) + 32) = u.s;
            } else {                                       // G = sigmoid(. + bg)
                const float4 b4 = *(const float4*)&bg[n0 - 192];
                U4 u;
                u.h[0] = f2bf(1.f/(1.f + __expf(-(c[0] + b4.x))));
                u.h[1] = f2bf(1.f/(1.f + __expf(-(c[1] + b4.y))));
                u.h[2] = f2bf(1.f/(1.f + __expf(-(c[2] + b4.z))));
                u.h[3] = f2bf(1.f/(1.f + __expf(-(c[3] + b4.w))));
                *(short4v*)(Gbuf + row*128 + (n0 - 192)) = u.s;
            }
        }
    }
}

// ---------------------------------------------------------------------------
// Kernel 2: attention. Block = (i, j-half), 512 threads = 8 waves.
// (R5 version, verified 115us: K,V head-independent -> staged once, shared by
// all 4 heads; wave w: head w>>1, j-tiles (jh*12 + (w&1)*6 + t)*16.
// LDS: Ks 30720 + Vt 25088 + Pb 18432 = 74240 B -> 2 blocks/CU = 16 waves/CU.
// Softmax exp2 domain, deferred normalization; per-wave 64-key Pb chunks.)
// ---------------------------------------------------------------------------
__global__ __launch_bounds__(512, 4) void k2_attn(
    const u16* __restrict__ KVbuf, const u16* __restrict__ Gbuf, u16* __restrict__ QObuf)
{
    __shared__ __align__(16) u16 Ks[384][40];      // K [key][c], +8 pad        30720 B
    __shared__ __align__(16) u16 Vt[32][392];      // V^T [c][key], +8 pad      25088 B
    __shared__ __align__(16) u16 Pb[8][16][72];    // per-wave P 64-key chunk   18432 B
    const int i = blockIdx.x >> 1, jh = blockIdx.x & 1;
    const int tid = threadIdx.x;
    const u16* kvsrc = KVbuf + (long)i * 384 * 64;
    {
        for (int idx = tid; idx < 384*8; idx += 512){
            const int k = idx >> 3, c8 = idx & 7;
            U8 d; d.s = *(const short8*)(kvsrc + k*64 + c8*8);
            if (c8 < 4) *(short8*)&Ks[k][c8*8] = d.s;
            else {
                const int c0 = (c8 - 4) * 8;
                #pragma unroll
                for (int jj = 0; jj < 8; jj++) Vt[c0 + jj][k] = d.h[jj];
            }
        }
    }
    __syncthreads();

    const int lane = tid & 63, wave = tid >> 6;
    const int l15 = lane & 15, quad = lane >> 4;
    const int h = wave >> 1, sub = wave & 1;
    const u16* qbase = QObuf + (long)i * 384 * 128 + h * 32;
    const u16* gbase = Gbuf  + (long)i * 384 * 128 + h * 32;
    u16* obase = QObuf + (long)i * 384 * 128 + h * 32;

    for (int t = 0; t < 6; t++){
        const int j0 = (jh*12 + sub*6 + t) * 16;
        // Q fragment straight from global (16B/lane, reused for 24 MFMAs)
        const short8 aq = *(const short8*)(qbase + (long)(j0 + l15)*128 + quad*8);
        float4v acc[24];
        #pragma unroll
        for (int kt = 0; kt < 24; kt++){
            const short8 bk = *(const short8*)&Ks[kt*16 + l15][quad*8];
            float4v zero = {0.f,0.f,0.f,0.f};
            acc[kt] = __builtin_amdgcn_mfma_f32_16x16x32_bf16(aq, bk, zero, 0, 0, 0);
        }
        // softmax along keys (exp2 domain); row r lives in this quad-group's 16 lanes.
        // P left UNNORMALIZED (2^(x-max) <= 1); inv folded into epilogue.
        float inv[4];
        #pragma unroll
        for (int r = 0; r < 4; r++){
            float mx = -1e30f;
            #pragma unroll
            for (int kt = 0; kt < 24; kt++) mx = fmaxf(mx, acc[kt][r]);
            mx = fmaxf(mx, __shfl_xor(mx, 1));
            mx = fmaxf(mx, __shfl_xor(mx, 2));
            mx = fmaxf(mx, __shfl_xor(mx, 4));
            mx = fmaxf(mx, __shfl_xor(mx, 8));
            float sum = 0.f;
            #pragma unroll
            for (int kt = 0; kt < 24; kt++){ acc[kt][r] = exp2_fast(acc[kt][r] - mx); sum += acc[kt][r]; }
            sum += __shfl_xor(sum, 1);
            sum += __shfl_xor(sum, 2);
            sum += __shfl_xor(sum, 4);
            sum += __shfl_xor(sum, 8);
            inv[r] = 1.f / sum;
        }
        // PV in 6 chunks of 64 keys: C-layout -> Pb -> A-layout (per-wave in-order LDS)
        float4v oacc[2] = {{0.f,0.f,0.f,0.f},{0.f,0.f,0.f,0.f}};
        #pragma unroll
        for (int cc = 0; cc < 6; cc++){
            #pragma unroll
            for (int j = 0; j < 4; j++){
                const int kt = cc*4 + j;
                #pragma unroll
                for (int r = 0; r < 4; r++)
                    Pb[wave][quad*4 + r][j*16 + l15] = f2bf(acc[kt][r]);
            }
            #pragma unroll
            for (int kj = 0; kj < 2; kj++){
                const int kk = cc*2 + kj;
                const short8 ap = *(const short8*)&Pb[wave][l15][kj*32 + quad*8];
                #pragma unroll
                for (int ct = 0; ct < 2; ct++){
                    const short8 bv = *(const short8*)&Vt[ct*16 + l15][kk*32 + quad*8];
                    oacc[ct] = __builtin_amdgcn_mfma_f32_16x16x32_bf16(ap, bv, oacc[ct], 0, 0, 0);
                }
            }
        }
        // gate + normalize + store (in-place over Q slice; Q for this j-tile consumed)
        #pragma unroll
        for (int ct = 0; ct < 2; ct++){
            const int c = ct*16 + l15;
            #pragma unroll
            for (int r = 0; r < 4; r++){
                const int row = j0 + quad*4 + r;
                const float gv = bf2f(gbase[(long)row*128 + c]);
                obase[(long)row*128 + c] = f2bf(gv * (oacc[ct][r] * inv[r]));
            }
        }
    }
}

// ---------------------------------------------------------------------------
// Kernel 3: out = O' @ Wo^T + bo   [147456x128]@[128x128] -> fp32 d_out
// R8: grid-stride x2 (1152 blocks x 2 slabs of 64 rows); W fragments + bias
// hoisted out of the slab loop (loaded once, reused 2x); (256,2) bounds.
// ---------------------------------------------------------------------------
__global__ __launch_bounds__(256, 2) void k3_outproj(
    const u16* __restrict__ Obuf, const u16* __restrict__ WoBf, const float* __restrict__ bo,
    float* __restrict__ out)
{
    const int tid = threadIdx.x, lane = tid & 63, wave = tid >> 6;
    const int l15 = lane & 15, quad = lane >> 4;
    short8 WF[2][4];
    float4 b4[2];
    #pragma unroll
    for (int g = 0; g < 2; g++){
        const u16* wp = WoBf + ((wave*2 + g)*16 + l15)*128 + quad*8;
        #pragma unroll
        for (int ks = 0; ks < 4; ks++) WF[g][ks] = *(const short8*)(wp + ks*32);
        b4[g] = *(const float4*)&bo[(wave*2 + g)*16 + quad*4];
    }
    #pragma unroll
    for (int slab = 0; slab < 2; slab++){
        const long row0 = ((long)blockIdx.x * 2 + slab) * 64;
        #pragma unroll
        for (int m = 0; m < 4; m++){
            short8 OF[4];
            const u16* ap = Obuf + (row0 + m*16 + l15)*128 + quad*8;
            #pragma unroll
            for (int ks = 0; ks < 4; ks++) OF[ks] = *(const short8*)(ap + ks*32);
            #pragma unroll
            for (int g = 0; g < 2; g++){
                float4v c = {0.f,0.f,0.f,0.f};
                #pragma unroll
                for (int ks = 0; ks < 4; ks++)
                    c = __builtin_amdgcn_mfma_f32_16x16x32_bf16(WF[g][ks], OF[ks], c, 0, 0, 0);
                const int n0 = (wave*2 + g)*16 + quad*4;
                const long row = row0 + m*16 + l15;
                float4 o4;
                o4.x = c[0] + b4[g].x; o4.y = c[1] + b4[g].y;
                o4.z = c[2] + b4[g].z; o4.w = c[3] + b4[g].w;
                *(float4*)(out + row*128 + n0) = o4;
            }
        }
    }
}

extern "C" void kernel_launch(void* const* d_in, const int* in_sizes, int n_in,
                              void* d_out, int out_size, void* d_ws, size_t ws_size,
                              hipStream_t stream)
{
    (void)in_sizes; (void)n_in; (void)out_size; (void)ws_size;
    const float* z   = (const float*)d_in[0];
    const float* lnw = (const float*)d_in[1];
    const float* lnb = (const float*)d_in[2];
    const float* Wq  = (const float*)d_in[3];
    const float* Wk  = (const float*)d_in[4];
    const float* Wv  = (const float*)d_in[5];
    // d_in[6] = Wb : softmax-invariant (broadcast along key axis) -> unused
    const float* Wg  = (const float*)d_in[7];
    const float* bg  = (const float*)d_in[8];
    const float* Wo  = (const float*)d_in[9];
    const float* bo  = (const float*)d_in[10];

    u16* Qbuf = (u16*)d_ws;                   // 147456*128 bf16 (Q, later O' in-place)
    u16* KV   = Qbuf + 147456L*128;           // 147456*64  bf16 (k | v)
    // G lives in d_out's front half (bf16, consumed by k2 before k3 overwrites
    // d_out with fp32 results). Wbf (320x128 bf16 = 80KB) lives right after G.
    u16* Gbuf = (u16*)d_out;                  // 147456*128 bf16 = 37.7MB < 75.5MB
    u16* Wbf  = Gbuf + 147456L*128;           // 40960 u16 = 80KB
    // WoBf overlays the (dead-after-k2) front of the KV region.
    u16* WoBf = KV;                           // 16384 u16 = 32KB

    k0a_wconv<<<dim3(20), dim3(256), 0, stream>>>(Wq, Wk, Wv, Wg, Wbf);
    k1_ln_proj<<<dim3(2304), dim3(256), 0, stream>>>(z, lnw, lnb, Wbf, bg,
                                                     Qbuf, KV, Gbuf);
    k2_attn<<<dim3(768), dim3(512), 0, stream>>>(KV, Gbuf, Qbuf);
    k0b_wconv<<<dim3(8), dim3(256), 0, stream>>>(Wo, WoBf);
    k3_outproj<<<dim3(1152), dim3(256), 0, stream>>>(Qbuf, WoBf, bo, (float*)d_out);
}